// Round 11
// baseline (817.759 us; speedup 1.0000x reference)
//
#include <hip/hip_runtime.h>
#include <hip/hip_bf16.h>

#define N_NODES 50000
#define N_EDGES 800000
#define NF      64
#define NG      50
#define NPG     (N_NODES / NG)   // 1000 nodes per graph
#define MCHUNK  20               // blocks per graph for means
#define MROWS   (NPG / MCHUNK)   // 50 nodes per means block
#define NTILES  (N_NODES / 16)   // 3125 exact
#define NB      64               // CSR-build blocks (one per node range)
#define NPB     782              // nodes per build block (64*782 = 50048 >= N)

typedef __attribute__((ext_vector_type(8))) short bf16x8;
typedef __attribute__((ext_vector_type(4))) float f32x4;
typedef unsigned short u16;

// round-half-up fp32->bf16 pair pack (inputs are finite)
__device__ inline unsigned pkbf(float a, float b) {
    unsigned ua = __float_as_uint(a) + 0x8000u;
    unsigned ub = __float_as_uint(b) + 0x8000u;
    return (ua >> 16) | (ub & 0xFFFF0000u);
}
__device__ inline short bf1(float a) {
    return (short)((__float_as_uint(a) + 0x8000u) >> 16);
}
__device__ inline float lo2f(unsigned u) { return __uint_as_float(u << 16); }
__device__ inline float hi2f(unsigned u) { return __uint_as_float(u & 0xFFFF0000u); }
__device__ inline void acc8(float* a, uint4 v) {
    a[0] += lo2f(v.x); a[1] += hi2f(v.x); a[2] += lo2f(v.y); a[3] += hi2f(v.y);
    a[4] += lo2f(v.z); a[5] += hi2f(v.z); a[6] += lo2f(v.w); a[7] += hi2f(v.w);
}

// ---------------------------------------------------------------------------
// CSR build pass 1: block b owns nodes [b*NPB, b*NPB+NPB); scans ALL cols,
// counts its nodes' degrees in LDS (col array is L2-resident; 8 co-XCD blocks
// share the fetch). Emits deg[], per-block edge total, and dmax.
__global__ __launch_bounds__(1024) void k_count(const int* __restrict__ col,
                                                int* __restrict__ deg,
                                                int* __restrict__ partials,
                                                int* __restrict__ dmax) {
    __shared__ int cnt[NPB];
    __shared__ int ss[16], mm[16];
    int b = blockIdx.x, t = threadIdx.x;
    int lo = b * NPB, hi = min(N_NODES, lo + NPB), n = hi - lo;
    for (int i = t; i < NPB; i += 1024) cnt[i] = 0;
    __syncthreads();
    for (int e = t; e < N_EDGES; e += 1024) {
        int c = col[e];
        if (c >= lo && c < hi) atomicAdd(&cnt[c - lo], 1);
    }
    __syncthreads();
    int s = 0, m = 0;
    for (int i = t; i < n; i += 1024) {
        int v = cnt[i];
        deg[lo + i] = v;
        s += v; m = max(m, v);
    }
    for (int off = 32; off; off >>= 1) {
        s += __shfl_xor(s, off, 64);
        m = max(m, __shfl_xor(m, off, 64));
    }
    if ((t & 63) == 0) { ss[t >> 6] = s; mm[t >> 6] = m; }
    __syncthreads();
    if (t == 0) {
        int S = 0, M = 0;
        for (int i = 0; i < 16; i++) { S += ss[i]; M = max(M, mm[i]); }
        partials[b] = S;
        atomicMax(dmax, M);
    }
}

// exclusive scan of the NB=64 block totals (one wave)
__global__ void k_scanp(int* __restrict__ partials, int* __restrict__ rowptr) {
    int t = threadIdx.x;              // 64 threads
    int v = partials[t];
    int inc = v;
    for (int off = 1; off < 64; off <<= 1) {
        int u = __shfl_up(inc, off, 64);
        if (t >= off) inc += u;
    }
    partials[t] = inc - v;            // exclusive global offset per block
    if (t == 63) rowptr[N_NODES] = N_EDGES;
}

// CSR build pass 2: local scan of deg -> rowptr/LDS cursors (global offsets),
// then rescan all edges placing row ids into the block's PRIVATE contiguous
// csr range (single writer per cache line -> no cross-XCD amplification).
__global__ __launch_bounds__(1024) void k_fill2(const int* __restrict__ row,
                                                const int* __restrict__ col,
                                                const int* __restrict__ deg,
                                                const int* __restrict__ partials,
                                                int* __restrict__ rowptr,
                                                u16* __restrict__ csr) {
    __shared__ int s[1024];
    __shared__ int cur[NPB];
    int b = blockIdx.x, t = threadIdx.x;
    int lo = b * NPB, hi = min(N_NODES, lo + NPB), n = hi - lo;
    int v = (t < n) ? deg[lo + t] : 0;
    s[t] = v;
    __syncthreads();
    for (int off = 1; off < 1024; off <<= 1) {
        int u = (t >= off) ? s[t - off] : 0;
        __syncthreads();
        s[t] += u;
        __syncthreads();
    }
    int ex = s[t] - v + partials[b];
    if (t < n) { rowptr[lo + t] = ex; cur[t] = ex; }
    __syncthreads();
    for (int e = t; e < N_EDGES; e += 1024) {
        int c = col[e];
        if (c >= lo && c < hi) {
            int pos = atomicAdd(&cur[c - lo], 1);
            csr[pos] = (u16)row[e];
        }
    }
}

// cur = relu(x @ W_init) bf16[N,64]; h = relu(x @ W_e1) bf16[N,64] (lane63=0)
__global__ void k_init(const float* __restrict__ x, const float* __restrict__ Wi,
                       const float* __restrict__ We1,
                       u16* __restrict__ cur, u16* __restrict__ h) {
    int idx = blockIdx.x * 256 + threadIdx.x;   // N*32
    int node = idx >> 5, q = idx & 31;
    if (node >= N_NODES) return;
    int f0 = 2 * q, f1 = 2 * q + 1;
    float4 xv = ((const float4*)x)[node];
    float c0 = xv.x * Wi[f0] + xv.y * Wi[64 + f0] + xv.z * Wi[128 + f0] + xv.w * Wi[192 + f0];
    float c1 = xv.x * Wi[f1] + xv.y * Wi[64 + f1] + xv.z * Wi[128 + f1] + xv.w * Wi[192 + f1];
    ((unsigned*)cur)[node * 32 + q] = pkbf(fmaxf(c0, 0.f), fmaxf(c1, 0.f));
    float h0 = xv.x * We1[f0] + xv.y * We1[63 + f0] + xv.z * We1[126 + f0] + xv.w * We1[189 + f0];
    h0 = fmaxf(h0, 0.f);
    float h1 = 0.f;
    if (f1 < 63) {
        h1 = xv.x * We1[f1] + xv.y * We1[63 + f1] + xv.z * We1[126 + f1] + xv.w * We1[189 + f1];
        h1 = fmaxf(h1, 0.f);
    }
    ((unsigned*)h)[node * 32 + q] = pkbf(h0, h1);
}

// Per-wave fused gather: lane (m = lane&15, q = lane>>4) accumulates features
// q*16..q*16+15 of node base+m over its edge list (fp32), normalizes by 1/deg,
// packs bf16, stores to wave-private swizzled LDS tile in MFMA A-layout.
__device__ inline void gather_tile(const u16* __restrict__ src,
                                   const int* __restrict__ rowptr,
                                   const u16* __restrict__ csr,
                                   int base, int m, int q, int wv,
                                   short (*AT)[16][64]) {
    int beg = rowptr[base + m], end = rowptr[base + m + 1];
    float ac[16];
#pragma unroll
    for (int i = 0; i < 16; i++) ac[i] = 0.f;
    int j = beg;
    for (; j + 1 < end; j += 2) {
        int r0 = csr[j], r1 = csr[j + 1];
        const uint4* p0 = (const uint4*)(src + (size_t)r0 * 64 + q * 16);
        const uint4* p1 = (const uint4*)(src + (size_t)r1 * 64 + q * 16);
        uint4 v00 = p0[0], v01 = p0[1];
        uint4 v10 = p1[0], v11 = p1[1];
        acc8(ac, v00); acc8(ac + 8, v01);
        acc8(ac, v10); acc8(ac + 8, v11);
    }
    if (j < end) {
        int r = csr[j];
        const uint4* p = (const uint4*)(src + (size_t)r * 64 + q * 16);
        uint4 v0 = p[0], v1 = p[1];
        acc8(ac, v0); acc8(ac + 8, v1);
    }
    float inv = 1.0f / (float)(end - beg);   // deg > 0 always
    uint4 lo, hi;
    lo.x = pkbf(ac[0] * inv,  ac[1] * inv);
    lo.y = pkbf(ac[2] * inv,  ac[3] * inv);
    lo.z = pkbf(ac[4] * inv,  ac[5] * inv);
    lo.w = pkbf(ac[6] * inv,  ac[7] * inv);
    hi.x = pkbf(ac[8] * inv,  ac[9] * inv);
    hi.y = pkbf(ac[10] * inv, ac[11] * inv);
    hi.z = pkbf(ac[12] * inv, ac[13] * inv);
    hi.w = pkbf(ac[14] * inv, ac[15] * inv);
    *(uint4*)&AT[wv][m][((2 * q) ^ (m & 7)) * 8]     = lo;
    *(uint4*)&AT[wv][m][((2 * q + 1) ^ (m & 7)) * 8] = hi;
}

// fused h-gather + edge_emb MFMA: A=[agg(h)(63) | deg/dmax], B=We2
__global__ __launch_bounds__(256) void k_edge_f(
        const u16* __restrict__ h, const int* __restrict__ rowptr,
        const u16* __restrict__ csr, const int* __restrict__ dmax,
        const float* __restrict__ We2, u16* __restrict__ ee) {
    __shared__ unsigned SB[2][4][64][4];   // 8KB
    __shared__ short AT[4][16][64];        // 8KB
    int t = threadIdx.x;
    for (int F = t; F < 512; F += 256) {
        int ks = F >> 8, tile = (F >> 6) & 3, ln = F & 63;
        int c = ln & 15, qq = ln >> 4;
        const float* W = We2 + (ks * 32 + qq * 8) * 64 + tile * 16 + c;
        unsigned d0 = pkbf(W[0],       W[64]);
        unsigned d1 = pkbf(W[2 * 64],  W[3 * 64]);
        unsigned d2 = pkbf(W[4 * 64],  W[5 * 64]);
        unsigned d3 = pkbf(W[6 * 64],  W[7 * 64]);
        int slot = ln ^ ((ln >> 3) & 7);
        SB[ks][tile][slot][0] = d0; SB[ks][tile][slot][1] = d1;
        SB[ks][tile][slot][2] = d2; SB[ks][tile][slot][3] = d3;
    }
    __syncthreads();
    int wv = t >> 6, lane = t & 63;
    int m = lane & 15, quad = lane >> 4;
    int slot = lane ^ ((lane >> 3) & 7);
    float idm = 1.0f / (float)dmax[0];
    for (int tb = blockIdx.x * 4 + wv; tb < NTILES; tb += gridDim.x * 4) {
        int base = tb * 16;
        gather_tile(h, rowptr, csr, base, m, quad, wv, AT);
        float dv = (float)(rowptr[base + m + 1] - rowptr[base + m]) * idm;
        f32x4 acc[4];
#pragma unroll
        for (int i = 0; i < 4; i++) acc[i] = (f32x4){0.f, 0.f, 0.f, 0.f};
#pragma unroll
        for (int ks = 0; ks < 2; ks++) {
            int gp = (ks * 4 + quad) ^ (m & 7);
            bf16x8 a = *(const bf16x8*)&AT[wv][m][gp * 8];
            if (ks == 1 && quad == 3) a[7] = bf1(dv);   // k=63 column
#pragma unroll
            for (int tile = 0; tile < 4; tile++) {
                bf16x8 b = *(const bf16x8*)&SB[ks][tile][slot][0];
                acc[tile] = __builtin_amdgcn_mfma_f32_16x16x32_bf16(a, b, acc[tile], 0, 0, 0);
            }
        }
#pragma unroll
        for (int tile = 0; tile < 4; tile++)
#pragma unroll
            for (int r = 0; r < 4; r++)
                ee[(size_t)(base + quad * 4 + r) * 64 + tile * 16 + m] =
                    (u16)bf1(fmaxf(acc[tile][r], 0.f));
    }
}

// fused gather + MPNN layer. XT serves as the agg tile (A-layout) during
// GEMM1 then is overwritten with the msg tile for GEMM2 — lifetimes are
// disjoint and DS ops are in-order per wave, so the union is safe (40KB LDS).
template <bool F32OUT>
__global__ __launch_bounds__(256) void k_flayer(
        const u16* __restrict__ cur, const u16* __restrict__ ee,
        const int* __restrict__ rowptr, const u16* __restrict__ csr,
        const float* __restrict__ Wm, const float* __restrict__ Wu,
        void* __restrict__ outp) {
    __shared__ unsigned SB[2][4][4][64][4];   // 32KB
    __shared__ short XT[4][16][64];           // 8KB agg tile, then msg tile
    int t = threadIdx.x;
    for (int F = t; F < 2048; F += 256) {
        int g = F >> 10, ks = (F >> 8) & 3, tile = (F >> 6) & 3, ln = F & 63;
        int c = ln & 15, qq = ln >> 4;
        const float* W = (g ? Wu : Wm) + (ks * 32 + qq * 8) * 64 + tile * 16 + c;
        unsigned d0 = pkbf(W[0],      W[64]);
        unsigned d1 = pkbf(W[2 * 64], W[3 * 64]);
        unsigned d2 = pkbf(W[4 * 64], W[5 * 64]);
        unsigned d3 = pkbf(W[6 * 64], W[7 * 64]);
        int slot = ln ^ ((ln >> 3) & 7);
        SB[g][ks][tile][slot][0] = d0; SB[g][ks][tile][slot][1] = d1;
        SB[g][ks][tile][slot][2] = d2; SB[g][ks][tile][slot][3] = d3;
    }
    __syncthreads();
    int wv = t >> 6, lane = t & 63;
    int m = lane & 15, quad = lane >> 4;
    int slot = lane ^ ((lane >> 3) & 7);
    for (int tb = blockIdx.x * 4 + wv; tb < NTILES; tb += gridDim.x * 4) {
        int base = tb * 16;
        gather_tile(cur, rowptr, csr, base, m, quad, wv, XT);
        const u16* erow = ee  + (size_t)(base + m) * 64;
        const u16* crow = cur + (size_t)(base + m) * 64;
        f32x4 acc[4];
#pragma unroll
        for (int i = 0; i < 4; i++) acc[i] = (f32x4){0.f, 0.f, 0.f, 0.f};
        // GEMM1: k 0..63 = agg (XT), 64..127 = ee (global)
#pragma unroll
        for (int ks = 0; ks < 4; ks++) {
            bf16x8 a;
            if (ks < 2) {
                int gp = (ks * 4 + quad) ^ (m & 7);
                a = *(const bf16x8*)&XT[wv][m][gp * 8];
            } else {
                a = *(const bf16x8*)(erow + (ks - 2) * 32 + quad * 8);
            }
#pragma unroll
            for (int tile = 0; tile < 4; tile++) {
                bf16x8 b = *(const bf16x8*)&SB[0][ks][tile][slot][0];
                acc[tile] = __builtin_amdgcn_mfma_f32_16x16x32_bf16(a, b, acc[tile], 0, 0, 0);
            }
        }
        // relu(msg) -> XT (reuse) in A-readable swizzled layout (wave-private)
#pragma unroll
        for (int tile = 0; tile < 4; tile++)
#pragma unroll
            for (int r = 0; r < 4; r++) {
                int node = quad * 4 + r;
                int f = tile * 16 + m;
                int sidx = (((f >> 3) ^ (node & 7)) << 3) | (f & 7);
                XT[wv][node][sidx] = bf1(fmaxf(acc[tile][r], 0.f));
            }
        // GEMM2: k 0..63 = cur (global bf16), 64..127 = msg (XT)
#pragma unroll
        for (int i = 0; i < 4; i++) acc[i] = (f32x4){0.f, 0.f, 0.f, 0.f};
#pragma unroll
        for (int ks = 0; ks < 4; ks++) {
            bf16x8 a;
            if (ks < 2) {
                a = *(const bf16x8*)(crow + ks * 32 + quad * 8);
            } else {
                int gp = ((ks - 2) * 4 + quad) ^ (m & 7);
                a = *(const bf16x8*)&XT[wv][m][gp << 3];
            }
#pragma unroll
            for (int tile = 0; tile < 4; tile++) {
                bf16x8 b = *(const bf16x8*)&SB[1][ks][tile][slot][0];
                acc[tile] = __builtin_amdgcn_mfma_f32_16x16x32_bf16(a, b, acc[tile], 0, 0, 0);
            }
        }
#pragma unroll
        for (int tile = 0; tile < 4; tile++)
#pragma unroll
            for (int r = 0; r < 4; r++) {
                float v = fmaxf(acc[tile][r], 0.f);
                size_t oi = (size_t)(base + quad * 4 + r) * 64 + tile * 16 + m;
                if (F32OUT) ((float*)outp)[oi] = v;
                else        ((u16*)outp)[oi] = (u16)bf1(v);
            }
    }
}

// per-graph mean of cur (fp32 final layer); 20 blocks/graph
__global__ void k_means(const float* __restrict__ cur, float* __restrict__ means) {
    int g = blockIdx.x / MCHUNK;
    int c = blockIdx.x % MCHUNK;
    int t = threadIdx.x, f = t & 63, q = t >> 6;
    int base = g * NPG + c * MROWS;
    float acc = 0.f;
    for (int n = base + q; n < base + MROWS; n += 4) acc += cur[(size_t)n * 64 + f];
    __shared__ float red[4][64];
    red[q][f] = acc;
    __syncthreads();
    if (q == 0)
        atomicAdd(&means[g * 64 + f],
                  (red[0][f] + red[1][f] + red[2][f] + red[3][f]) * (1.0f / NPG));
}

// r1[g] = sum_f relu((means[g] @ Wp)[f]) * Wr[f]  -- 50 graphs, 1 block
__global__ __launch_bounds__(256) void k_pool(
        const float* __restrict__ means, const float* __restrict__ Wp,
        const float* __restrict__ Wr, float* __restrict__ r1) {
    int wv = threadIdx.x >> 6, lane = threadIdx.x & 63;
    for (int g = wv; g < NG; g += 4) {
        float acc = 0.f;
#pragma unroll 16
        for (int k = 0; k < 64; k++) acc = fmaf(means[g * 64 + k], Wp[k * 64 + lane], acc);
        float v = fmaxf(acc, 0.f) * Wr[lane];
        for (int off = 32; off; off >>= 1) v += __shfl_xor(v, off, 64);
        if (lane == 0) r1[g] = v;
    }
}

// out[n] = b + r1[batch[n]] + dot(relu(cur[n]), Wr[64:])  -- quarter-wave per node
__global__ void k_read2(const float* __restrict__ cur, const float* __restrict__ r1,
                        const int* __restrict__ batch, const float* __restrict__ Wr,
                        const float* __restrict__ br, float* __restrict__ out) {
    int idx = blockIdx.x * 256 + threadIdx.x;
    int node = idx >> 4;
    if (node >= N_NODES) return;
    int q = idx & 15;
    float4 c = *(const float4*)(cur + (size_t)node * 64 + q * 4);
    float4 w = *(const float4*)(Wr + 64 + q * 4);
    float v = fmaxf(c.x, 0.f) * w.x + fmaxf(c.y, 0.f) * w.y
            + fmaxf(c.z, 0.f) * w.z + fmaxf(c.w, 0.f) * w.w;
    v += __shfl_xor(v, 1, 64); v += __shfl_xor(v, 2, 64);
    v += __shfl_xor(v, 4, 64); v += __shfl_xor(v, 8, 64);
    if (q == 0) out[node] = v + r1[batch[node]] + br[0];
}

// ---------------------------------------------------------------------------
extern "C" void kernel_launch(void* const* d_in, const int* in_sizes, int n_in,
                              void* d_out, int out_size, void* d_ws, size_t ws_size,
                              hipStream_t stream) {
    const float* x    = (const float*)d_in[0];
    const float* Wi   = (const float*)d_in[1];
    const float* We1  = (const float*)d_in[2];
    const float* We2  = (const float*)d_in[3];
    const float* Wm   = (const float*)d_in[4];   // [3,128,64]
    const float* Wu   = (const float*)d_in[5];   // [3,128,64]
    const float* Wp   = (const float*)d_in[6];
    const float* Wr   = (const float*)d_in[7];
    const float* br   = (const float*)d_in[8];
    const int*   ei   = (const int*)d_in[9];     // [2,E]
    const int*   batch= (const int*)d_in[10];
    const int* row = ei;
    const int* col = ei + N_EDGES;
    float* out = (float*)d_out;

    char* w = (char*)d_ws;
    size_t off = 0;
    auto carve = [&](size_t bytes) -> void* {
        void* p = (void*)(w + off);
        off += (bytes + 255) & ~(size_t)255;
        return p;
    };
    int*   deg      = (int*)carve((size_t)N_NODES * 4);
    int*   rowptr   = (int*)carve((size_t)(N_NODES + 1) * 4);
    u16*   csr      = (u16*)carve((size_t)N_EDGES * 2);
    int*   partials = (int*)carve((size_t)NB * 4);
    u16*   bufA     = (u16*)carve((size_t)N_NODES * 64 * 2);
    u16*   bufB     = (u16*)carve((size_t)N_NODES * 64 * 2);
    u16*   ee       = (u16*)carve((size_t)N_NODES * 64 * 2);
    float* curF     = (float*)carve((size_t)N_NODES * 64 * 4);
    float* means    = (float*)carve((size_t)NG * 64 * 4);
    float* r1       = (float*)carve((size_t)NG * 4);
    int*   dmax     = (int*)carve(256);

    hipMemsetAsync(dmax,  0, 4, stream);
    hipMemsetAsync(means, 0, (size_t)NG * 64 * 4, stream);

    // CSR build: per-block node-range ownership, LDS counting + LDS cursors
    k_count<<<NB, 1024, 0, stream>>>(col, deg, partials, dmax);
    k_scanp<<<1, 64, 0, stream>>>(partials, rowptr);
    k_fill2<<<NB, 1024, 0, stream>>>(row, col, deg, partials, rowptr, csr);

    k_init  <<<(N_NODES * 32 + 255) / 256, 256, 0, stream>>>(x, Wi, We1, bufA, bufB);

    // fused h-gather + edge embedding (bufB = h)
    k_edge_f<<<782, 256, 0, stream>>>(bufB, rowptr, csr, dmax, We2, ee);

    // fused gather+layer x3: A->B, B->A, A->curF(fp32)
    k_flayer<false><<<782, 256, 0, stream>>>(bufA, ee, rowptr, csr,
                                             Wm, Wu, bufB);
    k_flayer<false><<<782, 256, 0, stream>>>(bufB, ee, rowptr, csr,
                                             Wm + 128 * 64, Wu + 128 * 64, bufA);
    k_flayer<true> <<<782, 256, 0, stream>>>(bufA, ee, rowptr, csr,
                                             Wm + 2 * 128 * 64, Wu + 2 * 128 * 64, curF);

    k_means<<<NG * MCHUNK, 256, 0, stream>>>(curF, means);
    k_pool <<<1, 256, 0, stream>>>(means, Wp, Wr, r1);
    k_read2<<<(N_NODES * 16 + 255) / 256, 256, 0, stream>>>(curF, r1, batch, Wr, br, out);
}

// Round 12
// 349.111 us; speedup vs baseline: 2.3424x; 2.3424x over previous
//
#include <hip/hip_runtime.h>
#include <hip/hip_bf16.h>

#define N_NODES 50000
#define N_EDGES 800000
#define NF      64
#define NG      50
#define NPG     (N_NODES / NG)   // 1000 nodes per graph
#define SCAN_NBLK ((N_NODES + 255) / 256)   // 196
#define MCHUNK  20               // blocks per graph for means
#define MROWS   (NPG / MCHUNK)   // 50 nodes per means block
#define NTILES  (N_NODES / 16)   // 3125 exact
#define FP_CHUNKS 112
#define FP_CHSZ  ((N_EDGES + FP_CHUNKS - 1) / FP_CHUNKS)   // 7143
#define FP_NPP   (N_NODES / 8)   // 6250 nodes per partition

typedef __attribute__((ext_vector_type(8))) short bf16x8;
typedef __attribute__((ext_vector_type(4))) float f32x4;
typedef unsigned short u16;

// round-half-up fp32->bf16 pair pack (inputs are finite)
__device__ inline unsigned pkbf(float a, float b) {
    unsigned ua = __float_as_uint(a) + 0x8000u;
    unsigned ub = __float_as_uint(b) + 0x8000u;
    return (ua >> 16) | (ub & 0xFFFF0000u);
}
__device__ inline short bf1(float a) {
    return (short)((__float_as_uint(a) + 0x8000u) >> 16);
}
__device__ inline float lo2f(unsigned u) { return __uint_as_float(u << 16); }
__device__ inline float hi2f(unsigned u) { return __uint_as_float(u & 0xFFFF0000u); }
__device__ inline void acc8(float* a, uint4 v) {
    a[0] += lo2f(v.x); a[1] += hi2f(v.x); a[2] += lo2f(v.y); a[3] += hi2f(v.y);
    a[4] += lo2f(v.z); a[5] += hi2f(v.z); a[6] += lo2f(v.w); a[7] += hi2f(v.w);
}

// ---------------------------------------------------------------------------
// degree histogram, destination-partitioned: block b handles partition b&7
// (R11 lesson: block-owns-range builds with <=64 blocks are latency-bound;
//  896 blocks + global atomics is the right trade on this chip)
__global__ void k_deg(const int* __restrict__ col, int* __restrict__ deg) {
    int part = blockIdx.x & 7, chunk = blockIdx.x >> 3;
    int lo = part * FP_NPP, hi = lo + FP_NPP;
    int e0 = chunk * FP_CHSZ;
    int e1 = min(N_EDGES, e0 + FP_CHSZ);
    for (int e = e0 + threadIdx.x; e < e1; e += 256) {
        int c = col[e];
        if (c >= lo && c < hi) atomicAdd(&deg[c], 1);
    }
}

// ---- hierarchical scan (+ degmax folded in) ----
__global__ void k_blocksum(const int* __restrict__ deg, int* __restrict__ partials,
                           int* __restrict__ dmax) {
    int i = blockIdx.x * 256 + threadIdx.x;
    int d = (i < N_NODES) ? deg[i] : 0;
    int v = d, m = d;
    for (int off = 32; off; off >>= 1) {
        v += __shfl_xor(v, off, 64);
        m = max(m, __shfl_xor(m, off, 64));
    }
    __shared__ int s[4];
    if ((threadIdx.x & 63) == 0) {
        s[threadIdx.x >> 6] = v;
        atomicMax(dmax, m);
    }
    __syncthreads();
    if (threadIdx.x == 0) partials[blockIdx.x] = s[0] + s[1] + s[2] + s[3];
}

__global__ void k_scanpartials(int* __restrict__ partials, int* __restrict__ rowptr) {
    __shared__ int s[256];
    int t = threadIdx.x;
    int v = (t < SCAN_NBLK) ? partials[t] : 0;
    s[t] = v;
    __syncthreads();
    for (int off = 1; off < 256; off <<= 1) {
        int u = (t >= off) ? s[t - off] : 0;
        __syncthreads();
        s[t] += u;
        __syncthreads();
    }
    if (t < SCAN_NBLK) partials[t] = s[t] - v;
    if (t == 0) rowptr[N_NODES] = N_EDGES;
}

__global__ void k_scanfinal(const int* __restrict__ deg, const int* __restrict__ partials,
                            int* __restrict__ rowptr, int* __restrict__ cursor) {
    int t = threadIdx.x;
    int i = blockIdx.x * 256 + t;
    int v = (i < N_NODES) ? deg[i] : 0;
    __shared__ int s[256];
    s[t] = v;
    __syncthreads();
    for (int off = 1; off < 256; off <<= 1) {
        int u = (t >= off) ? s[t - off] : 0;
        __syncthreads();
        s[t] += u;
        __syncthreads();
    }
    int ex = s[t] - v + partials[blockIdx.x];
    if (i < N_NODES) { rowptr[i] = ex; cursor[i] = ex; }
}

// CSR fill (u16 payload: node ids < 65536), destination-partitioned
__global__ void k_fill(const int* __restrict__ row, const int* __restrict__ col,
                       int* __restrict__ cursor, u16* __restrict__ csr) {
    int part = blockIdx.x & 7, chunk = blockIdx.x >> 3;
    int lo = part * FP_NPP, hi = lo + FP_NPP;
    int e0 = chunk * FP_CHSZ;
    int e1 = min(N_EDGES, e0 + FP_CHSZ);
    for (int e = e0 + threadIdx.x; e < e1; e += 256) {
        int c = col[e];
        if (c >= lo && c < hi) {
            int pos = atomicAdd(&cursor[c], 1);
            csr[pos] = (u16)row[e];
        }
    }
}

// cur = relu(x @ W_init) bf16[N,64]; h = relu(x @ W_e1) bf16[N,64] (lane63=0)
__global__ void k_init(const float* __restrict__ x, const float* __restrict__ Wi,
                       const float* __restrict__ We1,
                       u16* __restrict__ cur, u16* __restrict__ h) {
    int idx = blockIdx.x * 256 + threadIdx.x;   // N*32
    int node = idx >> 5, q = idx & 31;
    if (node >= N_NODES) return;
    int f0 = 2 * q, f1 = 2 * q + 1;
    float4 xv = ((const float4*)x)[node];
    float c0 = xv.x * Wi[f0] + xv.y * Wi[64 + f0] + xv.z * Wi[128 + f0] + xv.w * Wi[192 + f0];
    float c1 = xv.x * Wi[f1] + xv.y * Wi[64 + f1] + xv.z * Wi[128 + f1] + xv.w * Wi[192 + f1];
    ((unsigned*)cur)[node * 32 + q] = pkbf(fmaxf(c0, 0.f), fmaxf(c1, 0.f));
    float h0 = xv.x * We1[f0] + xv.y * We1[63 + f0] + xv.z * We1[126 + f0] + xv.w * We1[189 + f0];
    h0 = fmaxf(h0, 0.f);
    float h1 = 0.f;
    if (f1 < 63) {
        h1 = xv.x * We1[f1] + xv.y * We1[63 + f1] + xv.z * We1[126 + f1] + xv.w * We1[189 + f1];
        h1 = fmaxf(h1, 0.f);
    }
    ((unsigned*)h)[node * 32 + q] = pkbf(h0, h1);
}

// Per-wave fused gather: lane (m = lane&15, q = lane>>4) accumulates features
// q*16..q*16+15 of node base+m over its edge list (fp32), normalizes by 1/deg,
// packs bf16, stores to wave-private swizzled LDS tile in MFMA A-layout.
__device__ inline void gather_tile(const u16* __restrict__ src,
                                   const int* __restrict__ rowptr,
                                   const u16* __restrict__ csr,
                                   int base, int m, int q, int wv,
                                   short (*AT)[16][64]) {
    int beg = rowptr[base + m], end = rowptr[base + m + 1];
    float ac[16];
#pragma unroll
    for (int i = 0; i < 16; i++) ac[i] = 0.f;
    int j = beg;
    for (; j + 1 < end; j += 2) {
        int r0 = csr[j], r1 = csr[j + 1];
        const uint4* p0 = (const uint4*)(src + (size_t)r0 * 64 + q * 16);
        const uint4* p1 = (const uint4*)(src + (size_t)r1 * 64 + q * 16);
        uint4 v00 = p0[0], v01 = p0[1];
        uint4 v10 = p1[0], v11 = p1[1];
        acc8(ac, v00); acc8(ac + 8, v01);
        acc8(ac, v10); acc8(ac + 8, v11);
    }
    if (j < end) {
        int r = csr[j];
        const uint4* p = (const uint4*)(src + (size_t)r * 64 + q * 16);
        uint4 v0 = p[0], v1 = p[1];
        acc8(ac, v0); acc8(ac + 8, v1);
    }
    float inv = 1.0f / (float)(end - beg);   // deg > 0 always
    uint4 lo, hi;
    lo.x = pkbf(ac[0] * inv,  ac[1] * inv);
    lo.y = pkbf(ac[2] * inv,  ac[3] * inv);
    lo.z = pkbf(ac[4] * inv,  ac[5] * inv);
    lo.w = pkbf(ac[6] * inv,  ac[7] * inv);
    hi.x = pkbf(ac[8] * inv,  ac[9] * inv);
    hi.y = pkbf(ac[10] * inv, ac[11] * inv);
    hi.z = pkbf(ac[12] * inv, ac[13] * inv);
    hi.w = pkbf(ac[14] * inv, ac[15] * inv);
    *(uint4*)&AT[wv][m][((2 * q) ^ (m & 7)) * 8]     = lo;
    *(uint4*)&AT[wv][m][((2 * q + 1) ^ (m & 7)) * 8] = hi;
}

// fused h-gather + edge_emb MFMA: A=[agg(h)(63) | deg/dmax], B=We2
__global__ __launch_bounds__(256) void k_edge_f(
        const u16* __restrict__ h, const int* __restrict__ rowptr,
        const u16* __restrict__ csr, const int* __restrict__ dmax,
        const float* __restrict__ We2, u16* __restrict__ ee) {
    __shared__ unsigned SB[2][4][64][4];   // 8KB
    __shared__ short AT[4][16][64];        // 8KB
    int t = threadIdx.x;
    for (int F = t; F < 512; F += 256) {
        int ks = F >> 8, tile = (F >> 6) & 3, ln = F & 63;
        int c = ln & 15, qq = ln >> 4;
        const float* W = We2 + (ks * 32 + qq * 8) * 64 + tile * 16 + c;
        unsigned d0 = pkbf(W[0],       W[64]);
        unsigned d1 = pkbf(W[2 * 64],  W[3 * 64]);
        unsigned d2 = pkbf(W[4 * 64],  W[5 * 64]);
        unsigned d3 = pkbf(W[6 * 64],  W[7 * 64]);
        int slot = ln ^ ((ln >> 3) & 7);
        SB[ks][tile][slot][0] = d0; SB[ks][tile][slot][1] = d1;
        SB[ks][tile][slot][2] = d2; SB[ks][tile][slot][3] = d3;
    }
    __syncthreads();
    int wv = t >> 6, lane = t & 63;
    int m = lane & 15, quad = lane >> 4;
    int slot = lane ^ ((lane >> 3) & 7);
    float idm = 1.0f / (float)dmax[0];
    for (int tb = blockIdx.x * 4 + wv; tb < NTILES; tb += gridDim.x * 4) {
        int base = tb * 16;
        gather_tile(h, rowptr, csr, base, m, quad, wv, AT);
        float dv = (float)(rowptr[base + m + 1] - rowptr[base + m]) * idm;
        f32x4 acc[4];
#pragma unroll
        for (int i = 0; i < 4; i++) acc[i] = (f32x4){0.f, 0.f, 0.f, 0.f};
#pragma unroll
        for (int ks = 0; ks < 2; ks++) {
            int gp = (ks * 4 + quad) ^ (m & 7);
            bf16x8 a = *(const bf16x8*)&AT[wv][m][gp * 8];
            if (ks == 1 && quad == 3) a[7] = bf1(dv);   // k=63 column
#pragma unroll
            for (int tile = 0; tile < 4; tile++) {
                bf16x8 b = *(const bf16x8*)&SB[ks][tile][slot][0];
                acc[tile] = __builtin_amdgcn_mfma_f32_16x16x32_bf16(a, b, acc[tile], 0, 0, 0);
            }
        }
#pragma unroll
        for (int tile = 0; tile < 4; tile++)
#pragma unroll
            for (int r = 0; r < 4; r++)
                ee[(size_t)(base + quad * 4 + r) * 64 + tile * 16 + m] =
                    (u16)bf1(fmaxf(acc[tile][r], 0.f));
    }
}

// fused gather + MPNN layer. XT serves as the agg tile (A-layout) during
// GEMM1 then is overwritten with the msg tile for GEMM2 — lifetimes are
// disjoint and DS ops are in-order per wave, so the union is safe (40KB LDS).
template <bool F32OUT>
__global__ __launch_bounds__(256) void k_flayer(
        const u16* __restrict__ cur, const u16* __restrict__ ee,
        const int* __restrict__ rowptr, const u16* __restrict__ csr,
        const float* __restrict__ Wm, const float* __restrict__ Wu,
        void* __restrict__ outp) {
    __shared__ unsigned SB[2][4][4][64][4];   // 32KB
    __shared__ short XT[4][16][64];           // 8KB agg tile, then msg tile
    int t = threadIdx.x;
    for (int F = t; F < 2048; F += 256) {
        int g = F >> 10, ks = (F >> 8) & 3, tile = (F >> 6) & 3, ln = F & 63;
        int c = ln & 15, qq = ln >> 4;
        const float* W = (g ? Wu : Wm) + (ks * 32 + qq * 8) * 64 + tile * 16 + c;
        unsigned d0 = pkbf(W[0],      W[64]);
        unsigned d1 = pkbf(W[2 * 64], W[3 * 64]);
        unsigned d2 = pkbf(W[4 * 64], W[5 * 64]);
        unsigned d3 = pkbf(W[6 * 64], W[7 * 64]);
        int slot = ln ^ ((ln >> 3) & 7);
        SB[g][ks][tile][slot][0] = d0; SB[g][ks][tile][slot][1] = d1;
        SB[g][ks][tile][slot][2] = d2; SB[g][ks][tile][slot][3] = d3;
    }
    __syncthreads();
    int wv = t >> 6, lane = t & 63;
    int m = lane & 15, quad = lane >> 4;
    int slot = lane ^ ((lane >> 3) & 7);
    for (int tb = blockIdx.x * 4 + wv; tb < NTILES; tb += gridDim.x * 4) {
        int base = tb * 16;
        gather_tile(cur, rowptr, csr, base, m, quad, wv, XT);
        const u16* erow = ee  + (size_t)(base + m) * 64;
        const u16* crow = cur + (size_t)(base + m) * 64;
        f32x4 acc[4];
#pragma unroll
        for (int i = 0; i < 4; i++) acc[i] = (f32x4){0.f, 0.f, 0.f, 0.f};
        // GEMM1: k 0..63 = agg (XT), 64..127 = ee (global)
#pragma unroll
        for (int ks = 0; ks < 4; ks++) {
            bf16x8 a;
            if (ks < 2) {
                int gp = (ks * 4 + quad) ^ (m & 7);
                a = *(const bf16x8*)&XT[wv][m][gp * 8];
            } else {
                a = *(const bf16x8*)(erow + (ks - 2) * 32 + quad * 8);
            }
#pragma unroll
            for (int tile = 0; tile < 4; tile++) {
                bf16x8 b = *(const bf16x8*)&SB[0][ks][tile][slot][0];
                acc[tile] = __builtin_amdgcn_mfma_f32_16x16x32_bf16(a, b, acc[tile], 0, 0, 0);
            }
        }
        // relu(msg) -> XT (reuse) in A-readable swizzled layout (wave-private)
#pragma unroll
        for (int tile = 0; tile < 4; tile++)
#pragma unroll
            for (int r = 0; r < 4; r++) {
                int node = quad * 4 + r;
                int f = tile * 16 + m;
                int sidx = (((f >> 3) ^ (node & 7)) << 3) | (f & 7);
                XT[wv][node][sidx] = bf1(fmaxf(acc[tile][r], 0.f));
            }
        // GEMM2: k 0..63 = cur (global bf16), 64..127 = msg (XT)
#pragma unroll
        for (int i = 0; i < 4; i++) acc[i] = (f32x4){0.f, 0.f, 0.f, 0.f};
#pragma unroll
        for (int ks = 0; ks < 4; ks++) {
            bf16x8 a;
            if (ks < 2) {
                a = *(const bf16x8*)(crow + ks * 32 + quad * 8);
            } else {
                int gp = ((ks - 2) * 4 + quad) ^ (m & 7);
                a = *(const bf16x8*)&XT[wv][m][gp << 3];
            }
#pragma unroll
            for (int tile = 0; tile < 4; tile++) {
                bf16x8 b = *(const bf16x8*)&SB[1][ks][tile][slot][0];
                acc[tile] = __builtin_amdgcn_mfma_f32_16x16x32_bf16(a, b, acc[tile], 0, 0, 0);
            }
        }
#pragma unroll
        for (int tile = 0; tile < 4; tile++)
#pragma unroll
            for (int r = 0; r < 4; r++) {
                float v = fmaxf(acc[tile][r], 0.f);
                size_t oi = (size_t)(base + quad * 4 + r) * 64 + tile * 16 + m;
                if (F32OUT) ((float*)outp)[oi] = v;
                else        ((u16*)outp)[oi] = (u16)bf1(v);
            }
    }
}

// per-graph mean of cur (fp32 final layer); 20 blocks/graph
__global__ void k_means(const float* __restrict__ cur, float* __restrict__ means) {
    int g = blockIdx.x / MCHUNK;
    int c = blockIdx.x % MCHUNK;
    int t = threadIdx.x, f = t & 63, q = t >> 6;
    int base = g * NPG + c * MROWS;
    float acc = 0.f;
    for (int n = base + q; n < base + MROWS; n += 4) acc += cur[(size_t)n * 64 + f];
    __shared__ float red[4][64];
    red[q][f] = acc;
    __syncthreads();
    if (q == 0)
        atomicAdd(&means[g * 64 + f],
                  (red[0][f] + red[1][f] + red[2][f] + red[3][f]) * (1.0f / NPG));
}

// r1[g] = sum_f relu((means[g] @ Wp)[f]) * Wr[f]  -- 50 graphs, 1 block
__global__ __launch_bounds__(256) void k_pool(
        const float* __restrict__ means, const float* __restrict__ Wp,
        const float* __restrict__ Wr, float* __restrict__ r1) {
    int wv = threadIdx.x >> 6, lane = threadIdx.x & 63;
    for (int g = wv; g < NG; g += 4) {
        float acc = 0.f;
#pragma unroll 16
        for (int k = 0; k < 64; k++) acc = fmaf(means[g * 64 + k], Wp[k * 64 + lane], acc);
        float v = fmaxf(acc, 0.f) * Wr[lane];
        for (int off = 32; off; off >>= 1) v += __shfl_xor(v, off, 64);
        if (lane == 0) r1[g] = v;
    }
}

// out[n] = b + r1[batch[n]] + dot(relu(cur[n]), Wr[64:])  -- quarter-wave per node
__global__ void k_read2(const float* __restrict__ cur, const float* __restrict__ r1,
                        const int* __restrict__ batch, const float* __restrict__ Wr,
                        const float* __restrict__ br, float* __restrict__ out) {
    int idx = blockIdx.x * 256 + threadIdx.x;
    int node = idx >> 4;
    if (node >= N_NODES) return;
    int q = idx & 15;
    float4 c = *(const float4*)(cur + (size_t)node * 64 + q * 4);
    float4 w = *(const float4*)(Wr + 64 + q * 4);
    float v = fmaxf(c.x, 0.f) * w.x + fmaxf(c.y, 0.f) * w.y
            + fmaxf(c.z, 0.f) * w.z + fmaxf(c.w, 0.f) * w.w;
    v += __shfl_xor(v, 1, 64); v += __shfl_xor(v, 2, 64);
    v += __shfl_xor(v, 4, 64); v += __shfl_xor(v, 8, 64);
    if (q == 0) out[node] = v + r1[batch[node]] + br[0];
}

// ---------------------------------------------------------------------------
extern "C" void kernel_launch(void* const* d_in, const int* in_sizes, int n_in,
                              void* d_out, int out_size, void* d_ws, size_t ws_size,
                              hipStream_t stream) {
    const float* x    = (const float*)d_in[0];
    const float* Wi   = (const float*)d_in[1];
    const float* We1  = (const float*)d_in[2];
    const float* We2  = (const float*)d_in[3];
    const float* Wm   = (const float*)d_in[4];   // [3,128,64]
    const float* Wu   = (const float*)d_in[5];   // [3,128,64]
    const float* Wp   = (const float*)d_in[6];
    const float* Wr   = (const float*)d_in[7];
    const float* br   = (const float*)d_in[8];
    const int*   ei   = (const int*)d_in[9];     // [2,E]
    const int*   batch= (const int*)d_in[10];
    const int* row = ei;
    const int* col = ei + N_EDGES;
    float* out = (float*)d_out;

    char* w = (char*)d_ws;
    size_t off = 0;
    auto carve = [&](size_t bytes) -> void* {
        void* p = (void*)(w + off);
        off += (bytes + 255) & ~(size_t)255;
        return p;
    };
    int*   deg      = (int*)carve((size_t)N_NODES * 4);
    int*   rowptr   = (int*)carve((size_t)(N_NODES + 1) * 4);
    int*   cursor   = (int*)carve((size_t)N_NODES * 4);
    u16*   csr      = (u16*)carve((size_t)N_EDGES * 2);
    int*   partials = (int*)carve((size_t)SCAN_NBLK * 4);
    u16*   bufA     = (u16*)carve((size_t)N_NODES * 64 * 2);
    u16*   bufB     = (u16*)carve((size_t)N_NODES * 64 * 2);
    u16*   ee       = (u16*)carve((size_t)N_NODES * 64 * 2);
    float* curF     = (float*)carve((size_t)N_NODES * 64 * 4);
    float* means    = (float*)carve((size_t)NG * 64 * 4);
    float* r1       = (float*)carve((size_t)NG * 4);
    int*   dmax     = (int*)carve(256);

    hipMemsetAsync(deg,   0, (size_t)N_NODES * 4, stream);
    hipMemsetAsync(dmax,  0, 4, stream);
    hipMemsetAsync(means, 0, (size_t)NG * 64 * 4, stream);

    // CSR build (destination-partitioned, 896 blocks — R10 known-good)
    k_deg         <<<FP_CHUNKS * 8, 256, 0, stream>>>(col, deg);
    k_blocksum    <<<SCAN_NBLK, 256, 0, stream>>>(deg, partials, dmax);
    k_scanpartials<<<1, 256, 0, stream>>>(partials, rowptr);
    k_scanfinal   <<<SCAN_NBLK, 256, 0, stream>>>(deg, partials, rowptr, cursor);
    k_fill        <<<FP_CHUNKS * 8, 256, 0, stream>>>(row, col, cursor, csr);

    k_init  <<<(N_NODES * 32 + 255) / 256, 256, 0, stream>>>(x, Wi, We1, bufA, bufB);

    // fused h-gather + edge embedding (bufB = h)
    k_edge_f<<<782, 256, 0, stream>>>(bufB, rowptr, csr, dmax, We2, ee);

    // fused gather+layer x3: A->B, B->A, A->curF(fp32)
    k_flayer<false><<<782, 256, 0, stream>>>(bufA, ee, rowptr, csr,
                                             Wm, Wu, bufB);
    k_flayer<false><<<782, 256, 0, stream>>>(bufB, ee, rowptr, csr,
                                             Wm + 128 * 64, Wu + 128 * 64, bufA);
    k_flayer<true> <<<782, 256, 0, stream>>>(bufA, ee, rowptr, csr,
                                             Wm + 2 * 128 * 64, Wu + 2 * 128 * 64, curF);

    k_means<<<NG * MCHUNK, 256, 0, stream>>>(curF, means);
    k_pool <<<1, 256, 0, stream>>>(means, Wp, Wr, r1);
    k_read2<<<(N_NODES * 16 + 255) / 256, 256, 0, stream>>>(curF, r1, batch, Wr, br, out);
}

// Round 13
// 343.059 us; speedup vs baseline: 2.3837x; 1.0176x over previous
//
#include <hip/hip_runtime.h>
#include <hip/hip_bf16.h>

#define N_NODES 50000
#define N_EDGES 800000
#define NF      64
#define NG      50
#define NPG     (N_NODES / NG)   // 1000 nodes per graph
#define SCAN_NBLK ((N_NODES + 255) / 256)   // 196
#define MCHUNK  20               // blocks per graph for means
#define MROWS   (NPG / MCHUNK)   // 50 nodes per means block
#define NTILES  (N_NODES / 16)   // 3125 exact
#define FP_CHUNKS 448            // R13: 4x chunks -> TLP hides atomic latency
#define FP_CHSZ  ((N_EDGES + FP_CHUNKS - 1) / FP_CHUNKS)   // 1786
#define FP_NPP   (N_NODES / 8)   // 6250 nodes per partition

typedef __attribute__((ext_vector_type(8))) short bf16x8;
typedef __attribute__((ext_vector_type(4))) float f32x4;
typedef unsigned short u16;

// round-half-up fp32->bf16 pair pack (inputs are finite)
__device__ inline unsigned pkbf(float a, float b) {
    unsigned ua = __float_as_uint(a) + 0x8000u;
    unsigned ub = __float_as_uint(b) + 0x8000u;
    return (ua >> 16) | (ub & 0xFFFF0000u);
}
__device__ inline short bf1(float a) {
    return (short)((__float_as_uint(a) + 0x8000u) >> 16);
}
__device__ inline float lo2f(unsigned u) { return __uint_as_float(u << 16); }
__device__ inline float hi2f(unsigned u) { return __uint_as_float(u & 0xFFFF0000u); }
__device__ inline void acc8(float* a, uint4 v) {
    a[0] += lo2f(v.x); a[1] += hi2f(v.x); a[2] += lo2f(v.y); a[3] += hi2f(v.y);
    a[4] += lo2f(v.z); a[5] += hi2f(v.z); a[6] += lo2f(v.w); a[7] += hi2f(v.w);
}

// ---------------------------------------------------------------------------
// degree histogram, destination-partitioned: block b handles partition b&7
__global__ void k_deg(const int* __restrict__ col, int* __restrict__ deg) {
    int part = blockIdx.x & 7, chunk = blockIdx.x >> 3;
    int lo = part * FP_NPP, hi = lo + FP_NPP;
    int e0 = chunk * FP_CHSZ;
    int e1 = min(N_EDGES, e0 + FP_CHSZ);
    for (int e = e0 + threadIdx.x; e < e1; e += 256) {
        int c = col[e];
        if (c >= lo && c < hi) atomicAdd(&deg[c], 1);
    }
}

// ---- hierarchical scan (+ degmax folded in) ----
__global__ void k_blocksum(const int* __restrict__ deg, int* __restrict__ partials,
                           int* __restrict__ dmax) {
    int i = blockIdx.x * 256 + threadIdx.x;
    int d = (i < N_NODES) ? deg[i] : 0;
    int v = d, m = d;
    for (int off = 32; off; off >>= 1) {
        v += __shfl_xor(v, off, 64);
        m = max(m, __shfl_xor(m, off, 64));
    }
    __shared__ int s[4];
    if ((threadIdx.x & 63) == 0) {
        s[threadIdx.x >> 6] = v;
        atomicMax(dmax, m);
    }
    __syncthreads();
    if (threadIdx.x == 0) partials[blockIdx.x] = s[0] + s[1] + s[2] + s[3];
}

__global__ void k_scanpartials(int* __restrict__ partials, int* __restrict__ rowptr) {
    __shared__ int s[256];
    int t = threadIdx.x;
    int v = (t < SCAN_NBLK) ? partials[t] : 0;
    s[t] = v;
    __syncthreads();
    for (int off = 1; off < 256; off <<= 1) {
        int u = (t >= off) ? s[t - off] : 0;
        __syncthreads();
        s[t] += u;
        __syncthreads();
    }
    if (t < SCAN_NBLK) partials[t] = s[t] - v;
    if (t == 0) rowptr[N_NODES] = N_EDGES;
}

__global__ void k_scanfinal(const int* __restrict__ deg, const int* __restrict__ partials,
                            int* __restrict__ rowptr, int* __restrict__ cursor) {
    int t = threadIdx.x;
    int i = blockIdx.x * 256 + t;
    int v = (i < N_NODES) ? deg[i] : 0;
    __shared__ int s[256];
    s[t] = v;
    __syncthreads();
    for (int off = 1; off < 256; off <<= 1) {
        int u = (t >= off) ? s[t - off] : 0;
        __syncthreads();
        s[t] += u;
        __syncthreads();
    }
    int ex = s[t] - v + partials[blockIdx.x];
    if (i < N_NODES) { rowptr[i] = ex; cursor[i] = ex; }
}

// CSR fill (u16 payload: node ids < 65536), destination-partitioned
__global__ void k_fill(const int* __restrict__ row, const int* __restrict__ col,
                       int* __restrict__ cursor, u16* __restrict__ csr) {
    int part = blockIdx.x & 7, chunk = blockIdx.x >> 3;
    int lo = part * FP_NPP, hi = lo + FP_NPP;
    int e0 = chunk * FP_CHSZ;
    int e1 = min(N_EDGES, e0 + FP_CHSZ);
    for (int e = e0 + threadIdx.x; e < e1; e += 256) {
        int c = col[e];
        if (c >= lo && c < hi) {
            int pos = atomicAdd(&cursor[c], 1);
            csr[pos] = (u16)row[e];
        }
    }
}

// cur = relu(x @ W_init) bf16[N,64]; h = relu(x @ W_e1) bf16[N,64] (lane63=0)
__global__ void k_init(const float* __restrict__ x, const float* __restrict__ Wi,
                       const float* __restrict__ We1,
                       u16* __restrict__ cur, u16* __restrict__ h) {
    int idx = blockIdx.x * 256 + threadIdx.x;   // N*32
    int node = idx >> 5, q = idx & 31;
    if (node >= N_NODES) return;
    int f0 = 2 * q, f1 = 2 * q + 1;
    float4 xv = ((const float4*)x)[node];
    float c0 = xv.x * Wi[f0] + xv.y * Wi[64 + f0] + xv.z * Wi[128 + f0] + xv.w * Wi[192 + f0];
    float c1 = xv.x * Wi[f1] + xv.y * Wi[64 + f1] + xv.z * Wi[128 + f1] + xv.w * Wi[192 + f1];
    ((unsigned*)cur)[node * 32 + q] = pkbf(fmaxf(c0, 0.f), fmaxf(c1, 0.f));
    float h0 = xv.x * We1[f0] + xv.y * We1[63 + f0] + xv.z * We1[126 + f0] + xv.w * We1[189 + f0];
    h0 = fmaxf(h0, 0.f);
    float h1 = 0.f;
    if (f1 < 63) {
        h1 = xv.x * We1[f1] + xv.y * We1[63 + f1] + xv.z * We1[126 + f1] + xv.w * We1[189 + f1];
        h1 = fmaxf(h1, 0.f);
    }
    ((unsigned*)h)[node * 32 + q] = pkbf(h0, h1);
}

// Per-wave fused gather: lane (m = lane&15, q = lane>>4) accumulates features
// q*16..q*16+15 of node base+m over its edge list (fp32), normalizes by 1/deg,
// packs bf16, stores to wave-private swizzled LDS tile in MFMA A-layout.
// 4-edge software pipeline: 8 uint4 loads in flight before first consume;
// accumulation into ac[] stays strictly sequential -> numerics identical.
__device__ inline void gather_tile(const u16* __restrict__ src,
                                   const int* __restrict__ rowptr,
                                   const u16* __restrict__ csr,
                                   int base, int m, int q, int wv,
                                   short (*AT)[16][64]) {
    int beg = rowptr[base + m], end = rowptr[base + m + 1];
    float ac[16];
#pragma unroll
    for (int i = 0; i < 16; i++) ac[i] = 0.f;
    int j = beg;
    for (; j + 3 < end; j += 4) {
        int r0 = csr[j], r1 = csr[j + 1], r2 = csr[j + 2], r3 = csr[j + 3];
        const uint4* p0 = (const uint4*)(src + (size_t)r0 * 64 + q * 16);
        const uint4* p1 = (const uint4*)(src + (size_t)r1 * 64 + q * 16);
        const uint4* p2 = (const uint4*)(src + (size_t)r2 * 64 + q * 16);
        const uint4* p3 = (const uint4*)(src + (size_t)r3 * 64 + q * 16);
        uint4 v00 = p0[0], v01 = p0[1];
        uint4 v10 = p1[0], v11 = p1[1];
        uint4 v20 = p2[0], v21 = p2[1];
        uint4 v30 = p3[0], v31 = p3[1];
        acc8(ac, v00); acc8(ac + 8, v01);
        acc8(ac, v10); acc8(ac + 8, v11);
        acc8(ac, v20); acc8(ac + 8, v21);
        acc8(ac, v30); acc8(ac + 8, v31);
    }
    for (; j < end; j++) {
        int r = csr[j];
        const uint4* p = (const uint4*)(src + (size_t)r * 64 + q * 16);
        uint4 v0 = p[0], v1 = p[1];
        acc8(ac, v0); acc8(ac + 8, v1);
    }
    float inv = 1.0f / (float)(end - beg);   // deg > 0 always
    uint4 lo, hi;
    lo.x = pkbf(ac[0] * inv,  ac[1] * inv);
    lo.y = pkbf(ac[2] * inv,  ac[3] * inv);
    lo.z = pkbf(ac[4] * inv,  ac[5] * inv);
    lo.w = pkbf(ac[6] * inv,  ac[7] * inv);
    hi.x = pkbf(ac[8] * inv,  ac[9] * inv);
    hi.y = pkbf(ac[10] * inv, ac[11] * inv);
    hi.z = pkbf(ac[12] * inv, ac[13] * inv);
    hi.w = pkbf(ac[14] * inv, ac[15] * inv);
    *(uint4*)&AT[wv][m][((2 * q) ^ (m & 7)) * 8]     = lo;
    *(uint4*)&AT[wv][m][((2 * q + 1) ^ (m & 7)) * 8] = hi;
}

// fused h-gather + edge_emb MFMA: A=[agg(h)(63) | deg/dmax], B=We2
__global__ __launch_bounds__(256) void k_edge_f(
        const u16* __restrict__ h, const int* __restrict__ rowptr,
        const u16* __restrict__ csr, const int* __restrict__ dmax,
        const float* __restrict__ We2, u16* __restrict__ ee) {
    __shared__ unsigned SB[2][4][64][4];   // 8KB
    __shared__ short AT[4][16][64];        // 8KB
    int t = threadIdx.x;
    for (int F = t; F < 512; F += 256) {
        int ks = F >> 8, tile = (F >> 6) & 3, ln = F & 63;
        int c = ln & 15, qq = ln >> 4;
        const float* W = We2 + (ks * 32 + qq * 8) * 64 + tile * 16 + c;
        unsigned d0 = pkbf(W[0],       W[64]);
        unsigned d1 = pkbf(W[2 * 64],  W[3 * 64]);
        unsigned d2 = pkbf(W[4 * 64],  W[5 * 64]);
        unsigned d3 = pkbf(W[6 * 64],  W[7 * 64]);
        int slot = ln ^ ((ln >> 3) & 7);
        SB[ks][tile][slot][0] = d0; SB[ks][tile][slot][1] = d1;
        SB[ks][tile][slot][2] = d2; SB[ks][tile][slot][3] = d3;
    }
    __syncthreads();
    int wv = t >> 6, lane = t & 63;
    int m = lane & 15, quad = lane >> 4;
    int slot = lane ^ ((lane >> 3) & 7);
    float idm = 1.0f / (float)dmax[0];
    for (int tb = blockIdx.x * 4 + wv; tb < NTILES; tb += gridDim.x * 4) {
        int base = tb * 16;
        gather_tile(h, rowptr, csr, base, m, quad, wv, AT);
        float dv = (float)(rowptr[base + m + 1] - rowptr[base + m]) * idm;
        f32x4 acc[4];
#pragma unroll
        for (int i = 0; i < 4; i++) acc[i] = (f32x4){0.f, 0.f, 0.f, 0.f};
#pragma unroll
        for (int ks = 0; ks < 2; ks++) {
            int gp = (ks * 4 + quad) ^ (m & 7);
            bf16x8 a = *(const bf16x8*)&AT[wv][m][gp * 8];
            if (ks == 1 && quad == 3) a[7] = bf1(dv);   // k=63 column
#pragma unroll
            for (int tile = 0; tile < 4; tile++) {
                bf16x8 b = *(const bf16x8*)&SB[ks][tile][slot][0];
                acc[tile] = __builtin_amdgcn_mfma_f32_16x16x32_bf16(a, b, acc[tile], 0, 0, 0);
            }
        }
#pragma unroll
        for (int tile = 0; tile < 4; tile++)
#pragma unroll
            for (int r = 0; r < 4; r++)
                ee[(size_t)(base + quad * 4 + r) * 64 + tile * 16 + m] =
                    (u16)bf1(fmaxf(acc[tile][r], 0.f));
    }
}

// fused gather + MPNN layer. XT serves as the agg tile (A-layout) during
// GEMM1 then is overwritten with the msg tile for GEMM2 — lifetimes are
// disjoint and DS ops are in-order per wave, so the union is safe (40KB LDS).
template <bool F32OUT>
__global__ __launch_bounds__(256) void k_flayer(
        const u16* __restrict__ cur, const u16* __restrict__ ee,
        const int* __restrict__ rowptr, const u16* __restrict__ csr,
        const float* __restrict__ Wm, const float* __restrict__ Wu,
        void* __restrict__ outp) {
    __shared__ unsigned SB[2][4][4][64][4];   // 32KB
    __shared__ short XT[4][16][64];           // 8KB agg tile, then msg tile
    int t = threadIdx.x;
    for (int F = t; F < 2048; F += 256) {
        int g = F >> 10, ks = (F >> 8) & 3, tile = (F >> 6) & 3, ln = F & 63;
        int c = ln & 15, qq = ln >> 4;
        const float* W = (g ? Wu : Wm) + (ks * 32 + qq * 8) * 64 + tile * 16 + c;
        unsigned d0 = pkbf(W[0],      W[64]);
        unsigned d1 = pkbf(W[2 * 64], W[3 * 64]);
        unsigned d2 = pkbf(W[4 * 64], W[5 * 64]);
        unsigned d3 = pkbf(W[6 * 64], W[7 * 64]);
        int slot = ln ^ ((ln >> 3) & 7);
        SB[g][ks][tile][slot][0] = d0; SB[g][ks][tile][slot][1] = d1;
        SB[g][ks][tile][slot][2] = d2; SB[g][ks][tile][slot][3] = d3;
    }
    __syncthreads();
    int wv = t >> 6, lane = t & 63;
    int m = lane & 15, quad = lane >> 4;
    int slot = lane ^ ((lane >> 3) & 7);
    for (int tb = blockIdx.x * 4 + wv; tb < NTILES; tb += gridDim.x * 4) {
        int base = tb * 16;
        gather_tile(cur, rowptr, csr, base, m, quad, wv, XT);
        const u16* erow = ee  + (size_t)(base + m) * 64;
        const u16* crow = cur + (size_t)(base + m) * 64;
        f32x4 acc[4];
#pragma unroll
        for (int i = 0; i < 4; i++) acc[i] = (f32x4){0.f, 0.f, 0.f, 0.f};
        // GEMM1: k 0..63 = agg (XT), 64..127 = ee (global)
#pragma unroll
        for (int ks = 0; ks < 4; ks++) {
            bf16x8 a;
            if (ks < 2) {
                int gp = (ks * 4 + quad) ^ (m & 7);
                a = *(const bf16x8*)&XT[wv][m][gp * 8];
            } else {
                a = *(const bf16x8*)(erow + (ks - 2) * 32 + quad * 8);
            }
#pragma unroll
            for (int tile = 0; tile < 4; tile++) {
                bf16x8 b = *(const bf16x8*)&SB[0][ks][tile][slot][0];
                acc[tile] = __builtin_amdgcn_mfma_f32_16x16x32_bf16(a, b, acc[tile], 0, 0, 0);
            }
        }
        // relu(msg) -> XT (reuse) in A-readable swizzled layout (wave-private)
#pragma unroll
        for (int tile = 0; tile < 4; tile++)
#pragma unroll
            for (int r = 0; r < 4; r++) {
                int node = quad * 4 + r;
                int f = tile * 16 + m;
                int sidx = (((f >> 3) ^ (node & 7)) << 3) | (f & 7);
                XT[wv][node][sidx] = bf1(fmaxf(acc[tile][r], 0.f));
            }
        // GEMM2: k 0..63 = cur (global bf16), 64..127 = msg (XT)
#pragma unroll
        for (int i = 0; i < 4; i++) acc[i] = (f32x4){0.f, 0.f, 0.f, 0.f};
#pragma unroll
        for (int ks = 0; ks < 4; ks++) {
            bf16x8 a;
            if (ks < 2) {
                a = *(const bf16x8*)(crow + ks * 32 + quad * 8);
            } else {
                int gp = ((ks - 2) * 4 + quad) ^ (m & 7);
                a = *(const bf16x8*)&XT[wv][m][gp << 3];
            }
#pragma unroll
            for (int tile = 0; tile < 4; tile++) {
                bf16x8 b = *(const bf16x8*)&SB[1][ks][tile][slot][0];
                acc[tile] = __builtin_amdgcn_mfma_f32_16x16x32_bf16(a, b, acc[tile], 0, 0, 0);
            }
        }
#pragma unroll
        for (int tile = 0; tile < 4; tile++)
#pragma unroll
            for (int r = 0; r < 4; r++) {
                float v = fmaxf(acc[tile][r], 0.f);
                size_t oi = (size_t)(base + quad * 4 + r) * 64 + tile * 16 + m;
                if (F32OUT) ((float*)outp)[oi] = v;
                else        ((u16*)outp)[oi] = (u16)bf1(v);
            }
    }
}

// per-graph mean of cur (fp32 final layer); 20 blocks/graph
__global__ void k_means(const float* __restrict__ cur, float* __restrict__ means) {
    int g = blockIdx.x / MCHUNK;
    int c = blockIdx.x % MCHUNK;
    int t = threadIdx.x, f = t & 63, q = t >> 6;
    int base = g * NPG + c * MROWS;
    float acc = 0.f;
    for (int n = base + q; n < base + MROWS; n += 4) acc += cur[(size_t)n * 64 + f];
    __shared__ float red[4][64];
    red[q][f] = acc;
    __syncthreads();
    if (q == 0)
        atomicAdd(&means[g * 64 + f],
                  (red[0][f] + red[1][f] + red[2][f] + red[3][f]) * (1.0f / NPG));
}

// r1[g] = sum_f relu((means[g] @ Wp)[f]) * Wr[f]  -- 50 graphs, 1 block
__global__ __launch_bounds__(256) void k_pool(
        const float* __restrict__ means, const float* __restrict__ Wp,
        const float* __restrict__ Wr, float* __restrict__ r1) {
    int wv = threadIdx.x >> 6, lane = threadIdx.x & 63;
    for (int g = wv; g < NG; g += 4) {
        float acc = 0.f;
#pragma unroll 16
        for (int k = 0; k < 64; k++) acc = fmaf(means[g * 64 + k], Wp[k * 64 + lane], acc);
        float v = fmaxf(acc, 0.f) * Wr[lane];
        for (int off = 32; off; off >>= 1) v += __shfl_xor(v, off, 64);
        if (lane == 0) r1[g] = v;
    }
}

// out[n] = b + r1[batch[n]] + dot(relu(cur[n]), Wr[64:])  -- quarter-wave per node
__global__ void k_read2(const float* __restrict__ cur, const float* __restrict__ r1,
                        const int* __restrict__ batch, const float* __restrict__ Wr,
                        const float* __restrict__ br, float* __restrict__ out) {
    int idx = blockIdx.x * 256 + threadIdx.x;
    int node = idx >> 4;
    if (node >= N_NODES) return;
    int q = idx & 15;
    float4 c = *(const float4*)(cur + (size_t)node * 64 + q * 4);
    float4 w = *(const float4*)(Wr + 64 + q * 4);
    float v = fmaxf(c.x, 0.f) * w.x + fmaxf(c.y, 0.f) * w.y
            + fmaxf(c.z, 0.f) * w.z + fmaxf(c.w, 0.f) * w.w;
    v += __shfl_xor(v, 1, 64); v += __shfl_xor(v, 2, 64);
    v += __shfl_xor(v, 4, 64); v += __shfl_xor(v, 8, 64);
    if (q == 0) out[node] = v + r1[batch[node]] + br[0];
}

// ---------------------------------------------------------------------------
extern "C" void kernel_launch(void* const* d_in, const int* in_sizes, int n_in,
                              void* d_out, int out_size, void* d_ws, size_t ws_size,
                              hipStream_t stream) {
    const float* x    = (const float*)d_in[0];
    const float* Wi   = (const float*)d_in[1];
    const float* We1  = (const float*)d_in[2];
    const float* We2  = (const float*)d_in[3];
    const float* Wm   = (const float*)d_in[4];   // [3,128,64]
    const float* Wu   = (const float*)d_in[5];   // [3,128,64]
    const float* Wp   = (const float*)d_in[6];
    const float* Wr   = (const float*)d_in[7];
    const float* br   = (const float*)d_in[8];
    const int*   ei   = (const int*)d_in[9];     // [2,E]
    const int*   batch= (const int*)d_in[10];
    const int* row = ei;
    const int* col = ei + N_EDGES;
    float* out = (float*)d_out;

    char* w = (char*)d_ws;
    size_t off = 0;
    auto carve = [&](size_t bytes) -> void* {
        void* p = (void*)(w + off);
        off += (bytes + 255) & ~(size_t)255;
        return p;
    };
    int*   deg      = (int*)carve((size_t)N_NODES * 4);
    int*   rowptr   = (int*)carve((size_t)(N_NODES + 1) * 4);
    int*   cursor   = (int*)carve((size_t)N_NODES * 4);
    u16*   csr      = (u16*)carve((size_t)N_EDGES * 2);
    int*   partials = (int*)carve((size_t)SCAN_NBLK * 4);
    u16*   bufA     = (u16*)carve((size_t)N_NODES * 64 * 2);
    u16*   bufB     = (u16*)carve((size_t)N_NODES * 64 * 2);
    u16*   ee       = (u16*)carve((size_t)N_NODES * 64 * 2);
    float* curF     = (float*)carve((size_t)N_NODES * 64 * 4);
    float* means    = (float*)carve((size_t)NG * 64 * 4);
    float* r1       = (float*)carve((size_t)NG * 4);
    int*   dmax     = (int*)carve(256);

    hipMemsetAsync(deg,   0, (size_t)N_NODES * 4, stream);
    hipMemsetAsync(dmax,  0, 4, stream);
    hipMemsetAsync(means, 0, (size_t)NG * 64 * 4, stream);

    // CSR build (destination-partitioned; 3584 blocks to hide atomic latency)
    k_deg         <<<FP_CHUNKS * 8, 256, 0, stream>>>(col, deg);
    k_blocksum    <<<SCAN_NBLK, 256, 0, stream>>>(deg, partials, dmax);
    k_scanpartials<<<1, 256, 0, stream>>>(partials, rowptr);
    k_scanfinal   <<<SCAN_NBLK, 256, 0, stream>>>(deg, partials, rowptr, cursor);
    k_fill        <<<FP_CHUNKS * 8, 256, 0, stream>>>(row, col, cursor, csr);

    k_init  <<<(N_NODES * 32 + 255) / 256, 256, 0, stream>>>(x, Wi, We1, bufA, bufB);

    // fused h-gather + edge embedding (bufB = h)
    k_edge_f<<<1024, 256, 0, stream>>>(bufB, rowptr, csr, dmax, We2, ee);

    // fused gather+layer x3: A->B, B->A, A->curF(fp32)
    k_flayer<false><<<1024, 256, 0, stream>>>(bufA, ee, rowptr, csr,
                                              Wm, Wu, bufB);
    k_flayer<false><<<1024, 256, 0, stream>>>(bufB, ee, rowptr, csr,
                                              Wm + 128 * 64, Wu + 128 * 64, bufA);
    k_flayer<true> <<<1024, 256, 0, stream>>>(bufA, ee, rowptr, csr,
                                              Wm + 2 * 128 * 64, Wu + 2 * 128 * 64, curF);

    k_means<<<NG * MCHUNK, 256, 0, stream>>>(curF, means);
    k_pool <<<1, 256, 0, stream>>>(means, Wp, Wr, r1);
    k_read2<<<(N_NODES * 16 + 255) / 256, 256, 0, stream>>>(curF, r1, batch, Wr, br, out);
}

// Round 14
// 339.058 us; speedup vs baseline: 2.4119x; 1.0118x over previous
//
#include <hip/hip_runtime.h>
#include <hip/hip_bf16.h>

#define N_NODES 50000
#define N_EDGES 800000
#define NF      64
#define NG      50
#define NPG     (N_NODES / NG)   // 1000 nodes per graph
#define SCAN_NBLK ((N_NODES + 255) / 256)   // 196
#define MCHUNK  20               // blocks per graph for means
#define MROWS   (NPG / MCHUNK)   // 50 nodes per means block
#define NTILES  (N_NODES / 16)   // 3125 exact
#define FP_CHUNKS 896            // R14: more TLP to hide returning-atomic latency
#define FP_CHSZ  ((N_EDGES + FP_CHUNKS - 1) / FP_CHUNKS)   // 893
#define FP_NPP   (N_NODES / 8)   // 6250 nodes per partition

typedef __attribute__((ext_vector_type(8))) short bf16x8;
typedef __attribute__((ext_vector_type(4))) float f32x4;
typedef unsigned short u16;

// round-half-up fp32->bf16 pair pack (inputs are finite)
__device__ inline unsigned pkbf(float a, float b) {
    unsigned ua = __float_as_uint(a) + 0x8000u;
    unsigned ub = __float_as_uint(b) + 0x8000u;
    return (ua >> 16) | (ub & 0xFFFF0000u);
}
__device__ inline short bf1(float a) {
    return (short)((__float_as_uint(a) + 0x8000u) >> 16);
}
__device__ inline float lo2f(unsigned u) { return __uint_as_float(u << 16); }
__device__ inline float hi2f(unsigned u) { return __uint_as_float(u & 0xFFFF0000u); }
// packed accumulate: float2 adds -> v_pk_add_f32 (2 f32 adds / inst)
__device__ inline void accp(float2* a, uint4 v) {
    a[0].x += lo2f(v.x); a[0].y += hi2f(v.x);
    a[1].x += lo2f(v.y); a[1].y += hi2f(v.y);
    a[2].x += lo2f(v.z); a[2].y += hi2f(v.z);
    a[3].x += lo2f(v.w); a[3].y += hi2f(v.w);
}

// ---------------------------------------------------------------------------
// degree histogram, destination-partitioned: block b handles partition b&7
__global__ void k_deg(const int* __restrict__ col, int* __restrict__ deg) {
    int part = blockIdx.x & 7, chunk = blockIdx.x >> 3;
    int lo = part * FP_NPP, hi = lo + FP_NPP;
    int e0 = chunk * FP_CHSZ;
    int e1 = min(N_EDGES, e0 + FP_CHSZ);
    for (int e = e0 + threadIdx.x; e < e1; e += 256) {
        int c = col[e];
        if (c >= lo && c < hi) atomicAdd(&deg[c], 1);
    }
}

// ---- hierarchical scan (+ degmax folded in) ----
__global__ void k_blocksum(const int* __restrict__ deg, int* __restrict__ partials,
                           int* __restrict__ dmax) {
    int i = blockIdx.x * 256 + threadIdx.x;
    int d = (i < N_NODES) ? deg[i] : 0;
    int v = d, m = d;
    for (int off = 32; off; off >>= 1) {
        v += __shfl_xor(v, off, 64);
        m = max(m, __shfl_xor(m, off, 64));
    }
    __shared__ int s[4];
    if ((threadIdx.x & 63) == 0) {
        s[threadIdx.x >> 6] = v;
        atomicMax(dmax, m);
    }
    __syncthreads();
    if (threadIdx.x == 0) partials[blockIdx.x] = s[0] + s[1] + s[2] + s[3];
}

__global__ void k_scanpartials(int* __restrict__ partials, int* __restrict__ rowptr) {
    __shared__ int s[256];
    int t = threadIdx.x;
    int v = (t < SCAN_NBLK) ? partials[t] : 0;
    s[t] = v;
    __syncthreads();
    for (int off = 1; off < 256; off <<= 1) {
        int u = (t >= off) ? s[t - off] : 0;
        __syncthreads();
        s[t] += u;
        __syncthreads();
    }
    if (t < SCAN_NBLK) partials[t] = s[t] - v;
    if (t == 0) rowptr[N_NODES] = N_EDGES;
}

__global__ void k_scanfinal(const int* __restrict__ deg, const int* __restrict__ partials,
                            int* __restrict__ rowptr, int* __restrict__ cursor) {
    int t = threadIdx.x;
    int i = blockIdx.x * 256 + t;
    int v = (i < N_NODES) ? deg[i] : 0;
    __shared__ int s[256];
    s[t] = v;
    __syncthreads();
    for (int off = 1; off < 256; off <<= 1) {
        int u = (t >= off) ? s[t - off] : 0;
        __syncthreads();
        s[t] += u;
        __syncthreads();
    }
    int ex = s[t] - v + partials[blockIdx.x];
    if (i < N_NODES) { rowptr[i] = ex; cursor[i] = ex; }
}

// CSR fill (u16 payload: node ids < 65536), destination-partitioned
__global__ void k_fill(const int* __restrict__ row, const int* __restrict__ col,
                       int* __restrict__ cursor, u16* __restrict__ csr) {
    int part = blockIdx.x & 7, chunk = blockIdx.x >> 3;
    int lo = part * FP_NPP, hi = lo + FP_NPP;
    int e0 = chunk * FP_CHSZ;
    int e1 = min(N_EDGES, e0 + FP_CHSZ);
    for (int e = e0 + threadIdx.x; e < e1; e += 256) {
        int c = col[e];
        if (c >= lo && c < hi) {
            int pos = atomicAdd(&cursor[c], 1);
            csr[pos] = (u16)row[e];
        }
    }
}

// cur = relu(x @ W_init) bf16[N,64]; h = relu(x @ W_e1) bf16[N,64] (lane63=0)
__global__ void k_init(const float* __restrict__ x, const float* __restrict__ Wi,
                       const float* __restrict__ We1,
                       u16* __restrict__ cur, u16* __restrict__ h) {
    int idx = blockIdx.x * 256 + threadIdx.x;   // N*32
    int node = idx >> 5, q = idx & 31;
    if (node >= N_NODES) return;
    int f0 = 2 * q, f1 = 2 * q + 1;
    float4 xv = ((const float4*)x)[node];
    float c0 = xv.x * Wi[f0] + xv.y * Wi[64 + f0] + xv.z * Wi[128 + f0] + xv.w * Wi[192 + f0];
    float c1 = xv.x * Wi[f1] + xv.y * Wi[64 + f1] + xv.z * Wi[128 + f1] + xv.w * Wi[192 + f1];
    ((unsigned*)cur)[node * 32 + q] = pkbf(fmaxf(c0, 0.f), fmaxf(c1, 0.f));
    float h0 = xv.x * We1[f0] + xv.y * We1[63 + f0] + xv.z * We1[126 + f0] + xv.w * We1[189 + f0];
    h0 = fmaxf(h0, 0.f);
    float h1 = 0.f;
    if (f1 < 63) {
        h1 = xv.x * We1[f1] + xv.y * We1[63 + f1] + xv.z * We1[126 + f1] + xv.w * We1[189 + f1];
        h1 = fmaxf(h1, 0.f);
    }
    ((unsigned*)h)[node * 32 + q] = pkbf(h0, h1);
}

// Per-wave fused gather: lane (m = lane&15, q = lane>>4) accumulates features
// q*16..q*16+15 of node base+m over its edge list (fp32 pairs -> v_pk_add_f32),
// normalizes by 1/deg, packs bf16, stores to wave-private swizzled LDS tile in
// MFMA A-layout. 4-edge software pipeline: 8 uint4 loads in flight before
// first consume; accumulation order strictly sequential -> numerics identical.
__device__ inline void gather_tile(const u16* __restrict__ src,
                                   const int* __restrict__ rowptr,
                                   const u16* __restrict__ csr,
                                   int base, int m, int q, int wv,
                                   short (*AT)[16][64]) {
    int beg = rowptr[base + m], end = rowptr[base + m + 1];
    float2 ac[8];
#pragma unroll
    for (int i = 0; i < 8; i++) ac[i] = make_float2(0.f, 0.f);
    int j = beg;
    for (; j + 3 < end; j += 4) {
        int r0 = csr[j], r1 = csr[j + 1], r2 = csr[j + 2], r3 = csr[j + 3];
        const uint4* p0 = (const uint4*)(src + (size_t)r0 * 64 + q * 16);
        const uint4* p1 = (const uint4*)(src + (size_t)r1 * 64 + q * 16);
        const uint4* p2 = (const uint4*)(src + (size_t)r2 * 64 + q * 16);
        const uint4* p3 = (const uint4*)(src + (size_t)r3 * 64 + q * 16);
        uint4 v00 = p0[0], v01 = p0[1];
        uint4 v10 = p1[0], v11 = p1[1];
        uint4 v20 = p2[0], v21 = p2[1];
        uint4 v30 = p3[0], v31 = p3[1];
        accp(ac, v00); accp(ac + 4, v01);
        accp(ac, v10); accp(ac + 4, v11);
        accp(ac, v20); accp(ac + 4, v21);
        accp(ac, v30); accp(ac + 4, v31);
    }
    for (; j < end; j++) {
        int r = csr[j];
        const uint4* p = (const uint4*)(src + (size_t)r * 64 + q * 16);
        uint4 v0 = p[0], v1 = p[1];
        accp(ac, v0); accp(ac + 4, v1);
    }
    float inv = 1.0f / (float)(end - beg);   // deg > 0 always
    uint4 lo, hi;
    lo.x = pkbf(ac[0].x * inv, ac[0].y * inv);
    lo.y = pkbf(ac[1].x * inv, ac[1].y * inv);
    lo.z = pkbf(ac[2].x * inv, ac[2].y * inv);
    lo.w = pkbf(ac[3].x * inv, ac[3].y * inv);
    hi.x = pkbf(ac[4].x * inv, ac[4].y * inv);
    hi.y = pkbf(ac[5].x * inv, ac[5].y * inv);
    hi.z = pkbf(ac[6].x * inv, ac[6].y * inv);
    hi.w = pkbf(ac[7].x * inv, ac[7].y * inv);
    *(uint4*)&AT[wv][m][((2 * q) ^ (m & 7)) * 8]     = lo;
    *(uint4*)&AT[wv][m][((2 * q + 1) ^ (m & 7)) * 8] = hi;
}

// fused h-gather + edge_emb MFMA: A=[agg(h)(63) | deg/dmax], B=We2
__global__ __launch_bounds__(256) void k_edge_f(
        const u16* __restrict__ h, const int* __restrict__ rowptr,
        const u16* __restrict__ csr, const int* __restrict__ dmax,
        const float* __restrict__ We2, u16* __restrict__ ee) {
    __shared__ unsigned SB[2][4][64][4];   // 8KB
    __shared__ short AT[4][16][64];        // 8KB
    int t = threadIdx.x;
    for (int F = t; F < 512; F += 256) {
        int ks = F >> 8, tile = (F >> 6) & 3, ln = F & 63;
        int c = ln & 15, qq = ln >> 4;
        const float* W = We2 + (ks * 32 + qq * 8) * 64 + tile * 16 + c;
        unsigned d0 = pkbf(W[0],       W[64]);
        unsigned d1 = pkbf(W[2 * 64],  W[3 * 64]);
        unsigned d2 = pkbf(W[4 * 64],  W[5 * 64]);
        unsigned d3 = pkbf(W[6 * 64],  W[7 * 64]);
        int slot = ln ^ ((ln >> 3) & 7);
        SB[ks][tile][slot][0] = d0; SB[ks][tile][slot][1] = d1;
        SB[ks][tile][slot][2] = d2; SB[ks][tile][slot][3] = d3;
    }
    __syncthreads();
    int wv = t >> 6, lane = t & 63;
    int m = lane & 15, quad = lane >> 4;
    int slot = lane ^ ((lane >> 3) & 7);
    float idm = 1.0f / (float)dmax[0];
    for (int tb = blockIdx.x * 4 + wv; tb < NTILES; tb += gridDim.x * 4) {
        int base = tb * 16;
        gather_tile(h, rowptr, csr, base, m, quad, wv, AT);
        float dv = (float)(rowptr[base + m + 1] - rowptr[base + m]) * idm;
        f32x4 acc[4];
#pragma unroll
        for (int i = 0; i < 4; i++) acc[i] = (f32x4){0.f, 0.f, 0.f, 0.f};
#pragma unroll
        for (int ks = 0; ks < 2; ks++) {
            int gp = (ks * 4 + quad) ^ (m & 7);
            bf16x8 a = *(const bf16x8*)&AT[wv][m][gp * 8];
            if (ks == 1 && quad == 3) a[7] = bf1(dv);   // k=63 column
#pragma unroll
            for (int tile = 0; tile < 4; tile++) {
                bf16x8 b = *(const bf16x8*)&SB[ks][tile][slot][0];
                acc[tile] = __builtin_amdgcn_mfma_f32_16x16x32_bf16(a, b, acc[tile], 0, 0, 0);
            }
        }
#pragma unroll
        for (int tile = 0; tile < 4; tile++)
#pragma unroll
            for (int r = 0; r < 4; r++)
                ee[(size_t)(base + quad * 4 + r) * 64 + tile * 16 + m] =
                    (u16)bf1(fmaxf(acc[tile][r], 0.f));
    }
}

// fused gather + MPNN layer. XT serves as the agg tile (A-layout) during
// GEMM1 then is overwritten with the msg tile for GEMM2 — lifetimes are
// disjoint and DS ops are in-order per wave, so the union is safe (40KB LDS).
template <bool F32OUT>
__global__ __launch_bounds__(256) void k_flayer(
        const u16* __restrict__ cur, const u16* __restrict__ ee,
        const int* __restrict__ rowptr, const u16* __restrict__ csr,
        const float* __restrict__ Wm, const float* __restrict__ Wu,
        void* __restrict__ outp) {
    __shared__ unsigned SB[2][4][4][64][4];   // 32KB
    __shared__ short XT[4][16][64];           // 8KB agg tile, then msg tile
    int t = threadIdx.x;
    for (int F = t; F < 2048; F += 256) {
        int g = F >> 10, ks = (F >> 8) & 3, tile = (F >> 6) & 3, ln = F & 63;
        int c = ln & 15, qq = ln >> 4;
        const float* W = (g ? Wu : Wm) + (ks * 32 + qq * 8) * 64 + tile * 16 + c;
        unsigned d0 = pkbf(W[0],      W[64]);
        unsigned d1 = pkbf(W[2 * 64], W[3 * 64]);
        unsigned d2 = pkbf(W[4 * 64], W[5 * 64]);
        unsigned d3 = pkbf(W[6 * 64], W[7 * 64]);
        int slot = ln ^ ((ln >> 3) & 7);
        SB[g][ks][tile][slot][0] = d0; SB[g][ks][tile][slot][1] = d1;
        SB[g][ks][tile][slot][2] = d2; SB[g][ks][tile][slot][3] = d3;
    }
    __syncthreads();
    int wv = t >> 6, lane = t & 63;
    int m = lane & 15, quad = lane >> 4;
    int slot = lane ^ ((lane >> 3) & 7);
    for (int tb = blockIdx.x * 4 + wv; tb < NTILES; tb += gridDim.x * 4) {
        int base = tb * 16;
        gather_tile(cur, rowptr, csr, base, m, quad, wv, XT);
        const u16* erow = ee  + (size_t)(base + m) * 64;
        const u16* crow = cur + (size_t)(base + m) * 64;
        f32x4 acc[4];
#pragma unroll
        for (int i = 0; i < 4; i++) acc[i] = (f32x4){0.f, 0.f, 0.f, 0.f};
        // GEMM1: k 0..63 = agg (XT), 64..127 = ee (global)
#pragma unroll
        for (int ks = 0; ks < 4; ks++) {
            bf16x8 a;
            if (ks < 2) {
                int gp = (ks * 4 + quad) ^ (m & 7);
                a = *(const bf16x8*)&XT[wv][m][gp * 8];
            } else {
                a = *(const bf16x8*)(erow + (ks - 2) * 32 + quad * 8);
            }
#pragma unroll
            for (int tile = 0; tile < 4; tile++) {
                bf16x8 b = *(const bf16x8*)&SB[0][ks][tile][slot][0];
                acc[tile] = __builtin_amdgcn_mfma_f32_16x16x32_bf16(a, b, acc[tile], 0, 0, 0);
            }
        }
        // relu(msg) -> XT (reuse) in A-readable swizzled layout (wave-private)
#pragma unroll
        for (int tile = 0; tile < 4; tile++)
#pragma unroll
            for (int r = 0; r < 4; r++) {
                int node = quad * 4 + r;
                int f = tile * 16 + m;
                int sidx = (((f >> 3) ^ (node & 7)) << 3) | (f & 7);
                XT[wv][node][sidx] = bf1(fmaxf(acc[tile][r], 0.f));
            }
        // GEMM2: k 0..63 = cur (global bf16), 64..127 = msg (XT)
#pragma unroll
        for (int i = 0; i < 4; i++) acc[i] = (f32x4){0.f, 0.f, 0.f, 0.f};
#pragma unroll
        for (int ks = 0; ks < 4; ks++) {
            bf16x8 a;
            if (ks < 2) {
                a = *(const bf16x8*)(crow + ks * 32 + quad * 8);
            } else {
                int gp = ((ks - 2) * 4 + quad) ^ (m & 7);
                a = *(const bf16x8*)&XT[wv][m][gp << 3];
            }
#pragma unroll
            for (int tile = 0; tile < 4; tile++) {
                bf16x8 b = *(const bf16x8*)&SB[1][ks][tile][slot][0];
                acc[tile] = __builtin_amdgcn_mfma_f32_16x16x32_bf16(a, b, acc[tile], 0, 0, 0);
            }
        }
#pragma unroll
        for (int tile = 0; tile < 4; tile++)
#pragma unroll
            for (int r = 0; r < 4; r++) {
                float v = fmaxf(acc[tile][r], 0.f);
                size_t oi = (size_t)(base + quad * 4 + r) * 64 + tile * 16 + m;
                if (F32OUT) ((float*)outp)[oi] = v;
                else        ((u16*)outp)[oi] = (u16)bf1(v);
            }
    }
}

// per-graph mean of cur (fp32 final layer); 20 blocks/graph
__global__ void k_means(const float* __restrict__ cur, float* __restrict__ means) {
    int g = blockIdx.x / MCHUNK;
    int c = blockIdx.x % MCHUNK;
    int t = threadIdx.x, f = t & 63, q = t >> 6;
    int base = g * NPG + c * MROWS;
    float acc = 0.f;
    for (int n = base + q; n < base + MROWS; n += 4) acc += cur[(size_t)n * 64 + f];
    __shared__ float red[4][64];
    red[q][f] = acc;
    __syncthreads();
    if (q == 0)
        atomicAdd(&means[g * 64 + f],
                  (red[0][f] + red[1][f] + red[2][f] + red[3][f]) * (1.0f / NPG));
}

// r1[g] = sum_f relu((means[g] @ Wp)[f]) * Wr[f]  -- 50 graphs, 1 block
__global__ __launch_bounds__(256) void k_pool(
        const float* __restrict__ means, const float* __restrict__ Wp,
        const float* __restrict__ Wr, float* __restrict__ r1) {
    int wv = threadIdx.x >> 6, lane = threadIdx.x & 63;
    for (int g = wv; g < NG; g += 4) {
        float acc = 0.f;
#pragma unroll 16
        for (int k = 0; k < 64; k++) acc = fmaf(means[g * 64 + k], Wp[k * 64 + lane], acc);
        float v = fmaxf(acc, 0.f) * Wr[lane];
        for (int off = 32; off; off >>= 1) v += __shfl_xor(v, off, 64);
        if (lane == 0) r1[g] = v;
    }
}

// out[n] = b + r1[batch[n]] + dot(relu(cur[n]), Wr[64:])  -- quarter-wave per node
__global__ void k_read2(const float* __restrict__ cur, const float* __restrict__ r1,
                        const int* __restrict__ batch, const float* __restrict__ Wr,
                        const float* __restrict__ br, float* __restrict__ out) {
    int idx = blockIdx.x * 256 + threadIdx.x;
    int node = idx >> 4;
    if (node >= N_NODES) return;
    int q = idx & 15;
    float4 c = *(const float4*)(cur + (size_t)node * 64 + q * 4);
    float4 w = *(const float4*)(Wr + 64 + q * 4);
    float v = fmaxf(c.x, 0.f) * w.x + fmaxf(c.y, 0.f) * w.y
            + fmaxf(c.z, 0.f) * w.z + fmaxf(c.w, 0.f) * w.w;
    v += __shfl_xor(v, 1, 64); v += __shfl_xor(v, 2, 64);
    v += __shfl_xor(v, 4, 64); v += __shfl_xor(v, 8, 64);
    if (q == 0) out[node] = v + r1[batch[node]] + br[0];
}

// ---------------------------------------------------------------------------
extern "C" void kernel_launch(void* const* d_in, const int* in_sizes, int n_in,
                              void* d_out, int out_size, void* d_ws, size_t ws_size,
                              hipStream_t stream) {
    const float* x    = (const float*)d_in[0];
    const float* Wi   = (const float*)d_in[1];
    const float* We1  = (const float*)d_in[2];
    const float* We2  = (const float*)d_in[3];
    const float* Wm   = (const float*)d_in[4];   // [3,128,64]
    const float* Wu   = (const float*)d_in[5];   // [3,128,64]
    const float* Wp   = (const float*)d_in[6];
    const float* Wr   = (const float*)d_in[7];
    const float* br   = (const float*)d_in[8];
    const int*   ei   = (const int*)d_in[9];     // [2,E]
    const int*   batch= (const int*)d_in[10];
    const int* row = ei;
    const int* col = ei + N_EDGES;
    float* out = (float*)d_out;

    char* w = (char*)d_ws;
    size_t off = 0;
    auto carve = [&](size_t bytes) -> void* {
        void* p = (void*)(w + off);
        off += (bytes + 255) & ~(size_t)255;
        return p;
    };
    // zero-init region first (one memset covers deg + dmax + means)
    int*   deg      = (int*)carve((size_t)N_NODES * 4);
    int*   dmax     = (int*)carve(256);
    float* means    = (float*)carve((size_t)NG * 64 * 4);
    size_t zero_span = off;
    int*   rowptr   = (int*)carve((size_t)(N_NODES + 1) * 4);
    int*   cursor   = (int*)carve((size_t)N_NODES * 4);
    u16*   csr      = (u16*)carve((size_t)N_EDGES * 2);
    int*   partials = (int*)carve((size_t)SCAN_NBLK * 4);
    u16*   bufA     = (u16*)carve((size_t)N_NODES * 64 * 2);
    u16*   bufB     = (u16*)carve((size_t)N_NODES * 64 * 2);
    u16*   ee       = (u16*)carve((size_t)N_NODES * 64 * 2);
    float* curF     = (float*)carve((size_t)N_NODES * 64 * 4);
    float* r1       = (float*)carve((size_t)NG * 4);

    hipMemsetAsync(d_ws, 0, zero_span, stream);

    // CSR build (destination-partitioned; 7168 blocks to hide atomic latency)
    k_deg         <<<FP_CHUNKS * 8, 256, 0, stream>>>(col, deg);
    k_blocksum    <<<SCAN_NBLK, 256, 0, stream>>>(deg, partials, dmax);
    k_scanpartials<<<1, 256, 0, stream>>>(partials, rowptr);
    k_scanfinal   <<<SCAN_NBLK, 256, 0, stream>>>(deg, partials, rowptr, cursor);
    k_fill        <<<FP_CHUNKS * 8, 256, 0, stream>>>(row, col, cursor, csr);

    k_init  <<<(N_NODES * 32 + 255) / 256, 256, 0, stream>>>(x, Wi, We1, bufA, bufB);

    // fused h-gather + edge embedding (bufB = h)
    k_edge_f<<<1024, 256, 0, stream>>>(bufB, rowptr, csr, dmax, We2, ee);

    // fused gather+layer x3: A->B, B->A, A->curF(fp32)
    k_flayer<false><<<1024, 256, 0, stream>>>(bufA, ee, rowptr, csr,
                                              Wm, Wu, bufB);
    k_flayer<false><<<1024, 256, 0, stream>>>(bufB, ee, rowptr, csr,
                                              Wm + 128 * 64, Wu + 128 * 64, bufA);
    k_flayer<true> <<<1024, 256, 0, stream>>>(bufA, ee, rowptr, csr,
                                              Wm + 2 * 128 * 64, Wu + 2 * 128 * 64, curF);

    k_means<<<NG * MCHUNK, 256, 0, stream>>>(curF, means);
    k_pool <<<1, 256, 0, stream>>>(means, Wp, Wr, r1);
    k_read2<<<(N_NODES * 16 + 255) / 256, 256, 0, stream>>>(curF, r1, batch, Wr, br, out);
}